// Round 9
// baseline (5865.409 us; speedup 1.0000x reference)
//
#include <hip/hip_runtime.h>

#define ROWS 32768      // B*T
#define D 512
#define NCODES 8192
#define NSPLIT 4
#define CODES_PER_SPLIT (NCODES / NSPLIT)   // 2048
#define BM 128          // rows per block = 8 waves * 16
#define BN 256          // codes per tile (4 per lane)
#define BKK 32          // k per stage
#define KC 384          // OpenBLAS sgemm kc panel split (verified exact, rounds 4-8)

// compile-time float4 component select (loops fully unrolled)
__device__ __forceinline__ float f4c(const float4& v, int c) {
    return c == 0 ? v.x : (c == 1 ? v.y : (c == 2 ? v.z : v.w));
}

// numpy pairwise f32 sum of squares of a 512-float row (verified exact).
__device__ __forceinline__ float np_sumsq_512(const float* __restrict__ p) {
    float blk[4];
#pragma unroll
    for (int b = 0; b < 4; ++b) {
        const float* q = p + b * 128;
        float r[8];
#pragma unroll
        for (int j = 0; j < 8; ++j) r[j] = __fmul_rn(q[j], q[j]);
#pragma unroll
        for (int i = 1; i < 16; ++i)
#pragma unroll
            for (int j = 0; j < 8; ++j)
                r[j] = __fadd_rn(r[j], __fmul_rn(q[i * 8 + j], q[i * 8 + j]));
        blk[b] = __fadd_rn(__fadd_rn(__fadd_rn(r[0], r[1]), __fadd_rn(r[2], r[3])),
                           __fadd_rn(__fadd_rn(r[4], r[5]), __fadd_rn(r[6], r[7])));
    }
    return __fadd_rn(__fadd_rn(blk[0], blk[1]), __fadd_rn(blk[2], blk[3]));
}

// ---------------- kernel 1: row sums of squares ----------------
__global__ void k_rowsums(const float* __restrict__ zE, const float* __restrict__ cb,
                          float* __restrict__ sq, float* __restrict__ e2) {
    int row = blockIdx.x * 64 + threadIdx.x;
    if (row < ROWS) {
        sq[row] = np_sumsq_512(zE + (size_t)row * D);
    } else {
        e2[row - ROWS] = np_sumsq_512(cb + (size_t)(row - ROWS) * D);
    }
}

// A k-pair loader: 16 rows, wave-uniform address -> 16x s_load_dwordx2 (SGPRs)
__device__ __forceinline__ void loadA16(float2 (&a)[16], const float* __restrict__ zE,
                                        int rowBase, int wrow, int kabs) {
#pragma unroll
    for (int i = 0; i < 16; ++i)
        a[i] = *(const float2*)(zE + (size_t)(rowBase + wrow + i) * D + kabs);
}

// ---------------- kernel 2: distance GEMM + fused partial argmin ----------------
// 512 thr = 8 waves; wave owns 16 rows (A wave-uniform -> SGPR s_load, zero LDS,
// software-pipelined k-pair double buffer); lane owns 4 codes; B is the only LDS
// traffic (1 ds_read_b128 / 128 FMA-insts), double-buffered across stages.
// Grid is XCD-colocated: all 4 code-splits of a row-block on one XCD -> zE L2-hot.
// Numerics per (row,code): m = fl(chain(k=0..383) + chain(k=384..511)),
// sequential ascending-k FMA; dist = fl(fl(s-2m)+e2). Bit-exact (rounds 4-8).
__global__ __launch_bounds__(512, 1)
void k_argmin(const float* __restrict__ zE, const float* __restrict__ cb,
              const float* __restrict__ sq, const float* __restrict__ e2,
              uint2* __restrict__ part) {
    __shared__ float Bs[2][BKK][BN];    // 2 x 32 KiB

    const int p       = blockIdx.x;               // 0..1023
    const int xcd     = p & 7;
    const int sseq    = p >> 3;                   // 0..127
    const int cs      = sseq & 3;                 // code split
    const int rowBlk  = xcd + (sseq >> 2) * 8;    // 0..255, fixed XCD per row-block
    const int rowBase = rowBlk * BM;
    const int tid     = threadIdx.x;
    const int lane    = tid & 63;
    const int lane4   = lane * 4;
    const int wrow    = __builtin_amdgcn_readfirstlane((tid >> 6) * 16);
    const int scg4    = (tid & 63) * 4;           // staging: 4 codes
    const int sk0     = (tid >> 6) * 4;           // staging: 4 k's

    float srow[16];
#pragma unroll
    for (int i = 0; i < 16; ++i) srow[i] = sq[rowBase + wrow + i];

    float bvr = INFINITY;   // running best (row = lane) across tiles
    int   bir = 0;

    float acc[16][4], m1[16][4];
    int cur = 0;

    // prologue: stage B for gs=0 (ct=0, ks=0) into Bs[0]
    {
        const float* g = cb + (size_t)(cs * CODES_PER_SPLIT + scg4) * D + sk0;
        float4 r0 = *(const float4*)(g);
        float4 r1 = *(const float4*)(g + D);
        float4 r2 = *(const float4*)(g + 2 * D);
        float4 r3 = *(const float4*)(g + 3 * D);
#pragma unroll
        for (int j = 0; j < 4; ++j) {
            float4 w;
            w.x = f4c(r0, j); w.y = f4c(r1, j); w.z = f4c(r2, j); w.w = f4c(r3, j);
            *(float4*)&Bs[0][sk0 + j][scg4] = w;
        }
    }

#pragma unroll 1
    for (int gs = 0; gs < 128; ++gs) {            // (ct 0..7) x (ks 0..15)
        const int ct = gs >> 4;
        const int ks = gs & 15;
        const int codeBase = cs * CODES_PER_SPLIT + ct * BN;

        if (ks == 0) {
#pragma unroll
            for (int i = 0; i < 16; ++i)
#pragma unroll
                for (int j = 0; j < 4; ++j) { acc[i][j] = 0.0f; m1[i][j] = 0.0f; }
        }

        __syncthreads();                           // Bs[cur] ready

        // prefetch next stage's B tile into registers (overlaps compute)
        float4 n0, n1, n2, n3;
        if (gs < 127) {
            const int g2 = gs + 1;
            const int cb2 = cs * CODES_PER_SPLIT + (g2 >> 4) * BN;
            const float* g = cb + (size_t)(cb2 + scg4) * D + (g2 & 15) * BKK + sk0;
            n0 = *(const float4*)(g);
            n1 = *(const float4*)(g + D);
            n2 = *(const float4*)(g + 2 * D);
            n3 = *(const float4*)(g + 3 * D);
        }

        // compute stage: 16 k-pairs, A double-buffered in SGPRs
        {
            float2 aA[16], aB[16];
            loadA16(aA, zE, rowBase, wrow, ks * BKK);
#pragma unroll 1
            for (int kp = 0; kp < 16; kp += 2) {
                loadA16(aB, zE, rowBase, wrow, ks * BKK + 2 * (kp + 1));
#pragma unroll
                for (int kk = 0; kk < 2; ++kk) {   // k-pair kp
                    float4 b4 = *(const float4*)&Bs[cur][2 * kp + kk][lane4];
                    float bw[4] = {b4.x, b4.y, b4.z, b4.w};
#pragma unroll
                    for (int i = 0; i < 16; ++i) {
                        float a = kk ? aA[i].y : aA[i].x;
#pragma unroll
                        for (int j = 0; j < 4; ++j)
                            acc[i][j] = __builtin_fmaf(a, bw[j], acc[i][j]);
                    }
                }
                if (kp + 2 < 16)
                    loadA16(aA, zE, rowBase, wrow, ks * BKK + 2 * (kp + 2));
#pragma unroll
                for (int kk = 0; kk < 2; ++kk) {   // k-pair kp+1
                    float4 b4 = *(const float4*)&Bs[cur][2 * (kp + 1) + kk][lane4];
                    float bw[4] = {b4.x, b4.y, b4.z, b4.w};
#pragma unroll
                    for (int i = 0; i < 16; ++i) {
                        float a = kk ? aB[i].y : aB[i].x;
#pragma unroll
                        for (int j = 0; j < 4; ++j)
                            acc[i][j] = __builtin_fmaf(a, bw[j], acc[i][j]);
                    }
                }
            }
        }

        if (ks == KC / BKK - 1) {                  // close panel 1 (k=0..383)
#pragma unroll
            for (int i = 0; i < 16; ++i)
#pragma unroll
                for (int j = 0; j < 4; ++j) { m1[i][j] = acc[i][j]; acc[i][j] = 0.0f; }
        }

        if (ks == 15) {
            // finalize tile: dist = fl(fl(s - 2*fl(S1+S2)) + e2), ascending codes
            float4 e4 = *(const float4*)(e2 + codeBase + lane4);
            float ec[4] = {e4.x, e4.y, e4.z, e4.w};
#pragma unroll
            for (int i = 0; i < 16; ++i) {
                float v = INFINITY;
                int   x = 0;
#pragma unroll
                for (int j = 0; j < 4; ++j) {
                    float m = __fadd_rn(m1[i][j], acc[i][j]);
                    float d = __fadd_rn(__fsub_rn(srow[i], __fmul_rn(2.0f, m)), ec[j]);
                    if (d < v) { v = d; x = codeBase + lane4 + j; }
                }
#pragma unroll
                for (int off = 32; off; off >>= 1) {
                    float v2 = __shfl_xor(v, off);
                    int   x2 = __shfl_xor(x, off);
                    if (v2 < v || (v2 == v && x2 < x)) { v = v2; x = x2; }
                }
                if (lane == i) {
                    if (v < bvr || (v == bvr && x < bir)) { bvr = v; bir = x; }
                }
            }
        }

        if (gs < 127) {                            // write next stage into other buf
#pragma unroll
            for (int j = 0; j < 4; ++j) {
                float4 w;
                w.x = f4c(n0, j); w.y = f4c(n1, j); w.z = f4c(n2, j); w.w = f4c(n3, j);
                *(float4*)&Bs[cur ^ 1][sk0 + j][scg4] = w;
            }
        }
        cur ^= 1;
    }

    if (lane < 16)
        part[(size_t)(rowBase + wrow + lane) * NSPLIT + cs] =
            make_uint2(__float_as_uint(bvr), (unsigned)bir);
}

// ---------------- kernel 3: reduce partials -> ids (f32 output) ----------------
__global__ void k_pick(const uint2* __restrict__ part, int* __restrict__ ids,
                       float* __restrict__ outIds) {
    int rr = blockIdx.x * blockDim.x + threadIdx.x;
    if (rr >= ROWS) return;
    float bvv = __uint_as_float(part[(size_t)rr * NSPLIT].x);
    int   bii = (int)part[(size_t)rr * NSPLIT].y;
    for (int cs2 = 1; cs2 < NSPLIT; ++cs2) {
        float v = __uint_as_float(part[(size_t)rr * NSPLIT + cs2].x);
        int   x = (int)part[(size_t)rr * NSPLIT + cs2].y;
        if (v < bvv || (v == bvv && x < bii)) { bvv = v; bii = x; }
    }
    bii = bii < 0 ? 0 : (bii > NCODES - 1 ? NCODES - 1 : bii);
    ids[rr] = bii;
    outIds[rr] = (float)bii;
}

// ---------------- kernel 4: gather z_q_st (f32) + loss partials ----------------
__global__ void k_gather(const float* __restrict__ zE, const float* __restrict__ cb,
                         const int* __restrict__ ids, float* __restrict__ outZ,
                         double* __restrict__ lossPart) {
    const int tid = threadIdx.x;
    double acc = 0.0;
#pragma unroll
    for (int it = 0; it < 4; ++it) {
        int chunk = blockIdx.x * 256 + tid + it * 1048576;   // float4 chunk id
        int row   = chunk >> 7;
        int koff  = (chunk & 127) << 2;
        int id    = ids[row];
        id = id < 0 ? 0 : (id > NCODES - 1 ? NCODES - 1 : id);
        float4 ze = *(const float4*)(zE + ((size_t)row << 9) + koff);
        float4 zq = *(const float4*)(cb + ((size_t)id << 9) + koff);
        float d0 = __fsub_rn(zq.x, ze.x);
        float d1 = __fsub_rn(zq.y, ze.y);
        float d2 = __fsub_rn(zq.z, ze.z);
        float d3 = __fsub_rn(zq.w, ze.w);
        float4 v;
        v.x = __fadd_rn(ze.x, d0);
        v.y = __fadd_rn(ze.y, d1);
        v.z = __fadd_rn(ze.z, d2);
        v.w = __fadd_rn(ze.w, d3);
        *reinterpret_cast<float4*>(outZ + ((size_t)chunk << 2)) = v;
        acc += (double)d0 * d0 + (double)d1 * d1 + (double)d2 * d2 + (double)d3 * d3;
    }
    for (int off = 32; off; off >>= 1) acc += __shfl_down(acc, off);
    __shared__ double sred[4];
    if ((tid & 63) == 0) sred[tid >> 6] = acc;
    __syncthreads();
    if (tid == 0) lossPart[blockIdx.x] = (sred[0] + sred[1]) + (sred[2] + sred[3]);
}

// ---------------- kernel 5: final loss (f32 output) ----------------
__global__ void k_loss(const double* __restrict__ lossPart, float* __restrict__ outLoss) {
    const int tid = threadIdx.x;
    double acc = 0.0;
    for (int i = tid; i < 4096; i += 256) acc += lossPart[i];
    for (int off = 32; off; off >>= 1) acc += __shfl_down(acc, off);
    __shared__ double sred[4];
    if ((tid & 63) == 0) sred[tid >> 6] = acc;
    __syncthreads();
    if (tid == 0) {
        double mean = ((sred[0] + sred[1]) + (sred[2] + sred[3])) / 16777216.0;
        float cl = (float)mean;
        *outLoss = __fadd_rn(cl, __fmul_rn(0.25f, cl));
    }
}

extern "C" void kernel_launch(void* const* d_in, const int* in_sizes, int n_in,
                              void* d_out, int out_size, void* d_ws, size_t ws_size,
                              hipStream_t stream) {
    (void)in_sizes; (void)n_in; (void)out_size; (void)ws_size;
    const float* zE = (const float*)d_in[0];
    const float* cb = (const float*)d_in[1];
    float* out = (float*)d_out;                    // f32 outputs, concatenated
    char* ws = (char*)d_ws;

    float*  sq       = (float*)(ws + 0);         // 32768 f32
    float*  e2       = (float*)(ws + 131072);    // 8192  f32
    int*    ids      = (int*)(ws + 163840);      // 32768 i32
    uint2*  part     = (uint2*)(ws + 294912);    // 32768*4 uint2 = 1 MiB
    double* lossPart = (double*)(ws + 1343488);  // 4096  f64

    k_rowsums<<<(ROWS + NCODES) / 64, 64, 0, stream>>>(zE, cb, sq, e2);
    k_argmin<<<1024, 512, 0, stream>>>(zE, cb, sq, e2, part);
    k_pick<<<ROWS / 256, 256, 0, stream>>>(part, ids, out + 16777216);
    k_gather<<<4096, 256, 0, stream>>>(zE, cb, ids, out, lossPart);
    k_loss<<<1, 256, 0, stream>>>(lossPart, out + 16777216 + 32768);
}

// Round 10
// 4019.755 us; speedup vs baseline: 1.4591x; 1.4591x over previous
//
#include <hip/hip_runtime.h>

#define ROWS 32768      // B*T
#define D 512
#define NCODES 8192
#define NSPLIT 4
#define CODES_PER_SPLIT (NCODES / NSPLIT)   // 2048
#define BM 32           // rows per block = 4 waves * 8
#define BN 256          // codes per tile (4 per lane)
#define BKK 32          // k per stage
#define KC 384          // OpenBLAS sgemm kc panel split (verified exact, rounds 4-9)

// compile-time float4 component select (loops fully unrolled)
__device__ __forceinline__ float f4c(const float4& v, int c) {
    return c == 0 ? v.x : (c == 1 ? v.y : (c == 2 ? v.z : v.w));
}

// numpy pairwise f32 sum of squares of a 512-float row (verified exact).
__device__ __forceinline__ float np_sumsq_512(const float* __restrict__ p) {
    float blk[4];
#pragma unroll
    for (int b = 0; b < 4; ++b) {
        const float* q = p + b * 128;
        float r[8];
#pragma unroll
        for (int j = 0; j < 8; ++j) r[j] = __fmul_rn(q[j], q[j]);
#pragma unroll
        for (int i = 1; i < 16; ++i)
#pragma unroll
            for (int j = 0; j < 8; ++j)
                r[j] = __fadd_rn(r[j], __fmul_rn(q[i * 8 + j], q[i * 8 + j]));
        blk[b] = __fadd_rn(__fadd_rn(__fadd_rn(r[0], r[1]), __fadd_rn(r[2], r[3])),
                           __fadd_rn(__fadd_rn(r[4], r[5]), __fadd_rn(r[6], r[7])));
    }
    return __fadd_rn(__fadd_rn(blk[0], blk[1]), __fadd_rn(blk[2], blk[3]));
}

// ---------------- kernel 1: row sums of squares ----------------
__global__ void k_rowsums(const float* __restrict__ zE, const float* __restrict__ cb,
                          float* __restrict__ sq, float* __restrict__ e2) {
    int row = blockIdx.x * 64 + threadIdx.x;
    if (row < ROWS) {
        sq[row] = np_sumsq_512(zE + (size_t)row * D);
    } else {
        e2[row - ROWS] = np_sumsq_512(cb + (size_t)(row - ROWS) * D);
    }
}

// ---------------- kernel 2: distance GEMM + fused partial argmin ----------------
// 256 thr = 4 waves; wave owns 8 rows -> A-reads are wave-uniform LDS broadcasts;
// lane owns 8 rows x 4 codes; B = 1 distinct ds_read_b128 per lane-k.
// 36 KiB LDS, ~110 VGPR -> 16 waves/CU (the r6-r9 regression was occupancy).
// Grid XCD-swizzled: XCD x serves only code-split x&3 -> 4 MiB cb slice L2-hot.
// Numerics per (row,code): m = fl(chain(k=0..383) + chain(k=384..511)),
// sequential ascending-k FMA; dist = fl(fl(s-2m)+e2). Bit-exact (rounds 4-9).
__global__ __launch_bounds__(256, 4)
void k_argmin(const float* __restrict__ zE, const float* __restrict__ cb,
              const float* __restrict__ sq, const float* __restrict__ e2,
              uint2* __restrict__ part) {
    __shared__ float As[BKK][BM];       // [k][row]   4 KiB
    __shared__ float Bs[BKK][BN];       // [k][code] 32 KiB

    // XCD-aware decode: dispatch round-robins blockIdx.x over 8 XCDs.
    const int p       = blockIdx.x;               // 0..4095
    const int x       = p & 7;                    // XCD
    const int s       = p >> 3;                   // 0..511
    const int cs      = x & 3;                    // code split, fixed per XCD
    const int rowBlk  = (x >> 2) * 512 + s;       // 0..1023
    const int rowBase = rowBlk * BM;
    const int tid     = threadIdx.x;
    const int lane    = tid & 63;
    const int lane4   = lane * 4;
    const int w8      = __builtin_amdgcn_readfirstlane((tid >> 6) * 8); // wave rows
    const int cg4     = (tid & 63) * 4;           // B-staging: 4 codes
    const int kq      = (tid >> 6) * 8;           // B-staging: 8 k's

    float srow[8];
#pragma unroll
    for (int i = 0; i < 8; ++i) srow[i] = sq[rowBase + w8 + i];

    float bvr[8];
    int   bir[8];
#pragma unroll
    for (int i = 0; i < 8; ++i) { bvr[i] = INFINITY; bir[i] = 0; }

    for (int ct = 0; ct < CODES_PER_SPLIT / BN; ++ct) {   // 8 code tiles
        const int codeBase = cs * CODES_PER_SPLIT + ct * BN;
        float acc[8][4], m1[8][4];
#pragma unroll
        for (int i = 0; i < 8; ++i)
#pragma unroll
            for (int j = 0; j < 4; ++j) { acc[i][j] = 0.0f; m1[i][j] = 0.0f; }

#pragma unroll 1
        for (int ks = 0; ks < D / BKK; ++ks) {            // 16 K stages, k ascending
            __syncthreads();
            if (tid < 128) {                              // stage A (4 KiB)
                int r  = tid >> 2;
                int k8 = (tid & 3) * 8;
                const float* gA = zE + (size_t)(rowBase + r) * D + ks * BKK + k8;
                float4 u = *(const float4*)(gA);
                float4 v = *(const float4*)(gA + 4);
                As[k8 + 0][r] = u.x;  As[k8 + 1][r] = u.y;
                As[k8 + 2][r] = u.z;  As[k8 + 3][r] = u.w;
                As[k8 + 4][r] = v.x;  As[k8 + 5][r] = v.y;
                As[k8 + 6][r] = v.z;  As[k8 + 7][r] = v.w;
            }
            {                                             // stage B (32 KiB), 4x4+4x4
                const float* g0 = cb + (size_t)(codeBase + cg4 + 0) * D + ks * BKK + kq;
                const float* g1 = cb + (size_t)(codeBase + cg4 + 1) * D + ks * BKK + kq;
                const float* g2 = cb + (size_t)(codeBase + cg4 + 2) * D + ks * BKK + kq;
                const float* g3 = cb + (size_t)(codeBase + cg4 + 3) * D + ks * BKK + kq;
                float4 u0 = *(const float4*)g0, v0 = *(const float4*)(g0 + 4);
                float4 u1 = *(const float4*)g1, v1 = *(const float4*)(g1 + 4);
                float4 u2 = *(const float4*)g2, v2 = *(const float4*)(g2 + 4);
                float4 u3 = *(const float4*)g3, v3 = *(const float4*)(g3 + 4);
#pragma unroll
                for (int j = 0; j < 4; ++j) {
                    float4 w;
                    w.x = f4c(u0, j); w.y = f4c(u1, j); w.z = f4c(u2, j); w.w = f4c(u3, j);
                    *(float4*)&Bs[kq + j][cg4] = w;
                }
#pragma unroll
                for (int j = 0; j < 4; ++j) {
                    float4 w;
                    w.x = f4c(v0, j); w.y = f4c(v1, j); w.z = f4c(v2, j); w.w = f4c(v3, j);
                    *(float4*)&Bs[kq + 4 + j][cg4] = w;
                }
            }
            __syncthreads();
#pragma unroll 4
            for (int k = 0; k < BKK; ++k) {               // ascending absolute k
                float4 a0 = *(const float4*)&As[k][w8];        // wave-uniform broadcast
                float4 a1 = *(const float4*)&As[k][w8 + 4];
                float4 b  = *(const float4*)&Bs[k][lane4];     // all 32 banks
                float av[8] = {a0.x, a0.y, a0.z, a0.w, a1.x, a1.y, a1.z, a1.w};
                float bw[4] = {b.x, b.y, b.z, b.w};
#pragma unroll
                for (int i = 0; i < 8; ++i)
#pragma unroll
                    for (int j = 0; j < 4; ++j)
                        acc[i][j] = __builtin_fmaf(av[i], bw[j], acc[i][j]);
            }
            if (ks == KC / BKK - 1) {                     // close panel 1 (k=0..383)
#pragma unroll
                for (int i = 0; i < 8; ++i)
#pragma unroll
                    for (int j = 0; j < 4; ++j) { m1[i][j] = acc[i][j]; acc[i][j] = 0.0f; }
            }
        }

        // finalize: dist = fl(fl(s - 2*fl(S1+S2)) + e2); ascending code order
        float4 e4 = *(const float4*)(e2 + codeBase + lane4);
        float ec[4] = {e4.x, e4.y, e4.z, e4.w};
#pragma unroll
        for (int j = 0; j < 4; ++j) {
            int c = codeBase + lane4 + j;
#pragma unroll
            for (int i = 0; i < 8; ++i) {
                float m = __fadd_rn(m1[i][j], acc[i][j]);
                float d = __fadd_rn(__fsub_rn(srow[i], __fmul_rn(2.0f, m)), ec[j]);
                if (d < bvr[i]) { bvr[i] = d; bir[i] = c; }
            }
        }
    }

    // wave-level lexicographic (val, idx) argmin reduce; lanes hold disjoint codes
#pragma unroll
    for (int i = 0; i < 8; ++i) {
        float v = bvr[i];
        int   xx = bir[i];
#pragma unroll
        for (int off = 32; off; off >>= 1) {
            float v2 = __shfl_xor(v, off);
            int   x2 = __shfl_xor(xx, off);
            if (v2 < v || (v2 == v && x2 < xx)) { v = v2; xx = x2; }
        }
        if (lane == 0)
            part[(size_t)(rowBase + w8 + i) * NSPLIT + cs] =
                make_uint2(__float_as_uint(v), (unsigned)xx);
    }
}

// ---------------- kernel 3: reduce partials -> ids (f32 output) ----------------
__global__ void k_pick(const uint2* __restrict__ part, int* __restrict__ ids,
                       float* __restrict__ outIds) {
    int rr = blockIdx.x * blockDim.x + threadIdx.x;
    if (rr >= ROWS) return;
    float bvv = __uint_as_float(part[(size_t)rr * NSPLIT].x);
    int   bii = (int)part[(size_t)rr * NSPLIT].y;
    for (int cs2 = 1; cs2 < NSPLIT; ++cs2) {
        float v = __uint_as_float(part[(size_t)rr * NSPLIT + cs2].x);
        int   x = (int)part[(size_t)rr * NSPLIT + cs2].y;
        if (v < bvv || (v == bvv && x < bii)) { bvv = v; bii = x; }
    }
    bii = bii < 0 ? 0 : (bii > NCODES - 1 ? NCODES - 1 : bii);
    ids[rr] = bii;
    outIds[rr] = (float)bii;
}

// ---------------- kernel 4: gather z_q_st (f32) + loss partials ----------------
__global__ void k_gather(const float* __restrict__ zE, const float* __restrict__ cb,
                         const int* __restrict__ ids, float* __restrict__ outZ,
                         double* __restrict__ lossPart) {
    const int tid = threadIdx.x;
    double acc = 0.0;
#pragma unroll
    for (int it = 0; it < 4; ++it) {
        int chunk = blockIdx.x * 256 + tid + it * 1048576;   // float4 chunk id
        int row   = chunk >> 7;
        int koff  = (chunk & 127) << 2;
        int id    = ids[row];
        id = id < 0 ? 0 : (id > NCODES - 1 ? NCODES - 1 : id);
        float4 ze = *(const float4*)(zE + ((size_t)row << 9) + koff);
        float4 zq = *(const float4*)(cb + ((size_t)id << 9) + koff);
        float d0 = __fsub_rn(zq.x, ze.x);
        float d1 = __fsub_rn(zq.y, ze.y);
        float d2 = __fsub_rn(zq.z, ze.z);
        float d3 = __fsub_rn(zq.w, ze.w);
        float4 v;
        v.x = __fadd_rn(ze.x, d0);
        v.y = __fadd_rn(ze.y, d1);
        v.z = __fadd_rn(ze.z, d2);
        v.w = __fadd_rn(ze.w, d3);
        *reinterpret_cast<float4*>(outZ + ((size_t)chunk << 2)) = v;
        acc += (double)d0 * d0 + (double)d1 * d1 + (double)d2 * d2 + (double)d3 * d3;
    }
    for (int off = 32; off; off >>= 1) acc += __shfl_down(acc, off);
    __shared__ double sred[4];
    if ((tid & 63) == 0) sred[tid >> 6] = acc;
    __syncthreads();
    if (tid == 0) lossPart[blockIdx.x] = (sred[0] + sred[1]) + (sred[2] + sred[3]);
}

// ---------------- kernel 5: final loss (f32 output) ----------------
__global__ void k_loss(const double* __restrict__ lossPart, float* __restrict__ outLoss) {
    const int tid = threadIdx.x;
    double acc = 0.0;
    for (int i = tid; i < 4096; i += 256) acc += lossPart[i];
    for (int off = 32; off; off >>= 1) acc += __shfl_down(acc, off);
    __shared__ double sred[4];
    if ((tid & 63) == 0) sred[tid >> 6] = acc;
    __syncthreads();
    if (tid == 0) {
        double mean = ((sred[0] + sred[1]) + (sred[2] + sred[3])) / 16777216.0;
        float cl = (float)mean;
        *outLoss = __fadd_rn(cl, __fmul_rn(0.25f, cl));
    }
}

extern "C" void kernel_launch(void* const* d_in, const int* in_sizes, int n_in,
                              void* d_out, int out_size, void* d_ws, size_t ws_size,
                              hipStream_t stream) {
    (void)in_sizes; (void)n_in; (void)out_size; (void)ws_size;
    const float* zE = (const float*)d_in[0];
    const float* cb = (const float*)d_in[1];
    float* out = (float*)d_out;                    // f32 outputs, concatenated
    char* ws = (char*)d_ws;

    float*  sq       = (float*)(ws + 0);         // 32768 f32
    float*  e2       = (float*)(ws + 131072);    // 8192  f32
    int*    ids      = (int*)(ws + 163840);      // 32768 i32
    uint2*  part     = (uint2*)(ws + 294912);    // 32768*4 uint2 = 1 MiB
    double* lossPart = (double*)(ws + 1343488);  // 4096  f64

    k_rowsums<<<(ROWS + NCODES) / 64, 64, 0, stream>>>(zE, cb, sq, e2);
    k_argmin<<<NSPLIT * (ROWS / BM), 256, 0, stream>>>(zE, cb, sq, e2, part);
    k_pick<<<ROWS / 256, 256, 0, stream>>>(part, ids, out + 16777216);
    k_gather<<<4096, 256, 0, stream>>>(zE, cb, ids, out, lossPart);
    k_loss<<<1, 256, 0, stream>>>(lossPart, out + 16777216 + 32768);
}

// Round 11
// 3923.972 us; speedup vs baseline: 1.4948x; 1.0244x over previous
//
#include <hip/hip_runtime.h>

#define ROWS 32768      // B*T
#define D 512
#define NCODES 8192
#define NSPLIT 4
#define CODES_PER_SPLIT (NCODES / NSPLIT)   // 2048
#define BM 32           // rows per block = 4 waves * 8
#define BN 256          // codes per tile (4 per lane)
#define BKK 32          // k per stage
#define KC 384          // OpenBLAS sgemm kc panel split (verified exact, rounds 4-10)

// compile-time float4 component select (loops fully unrolled)
__device__ __forceinline__ float f4c(const float4& v, int c) {
    return c == 0 ? v.x : (c == 1 ? v.y : (c == 2 ? v.z : v.w));
}

// numpy pairwise f32 sum of squares of a 512-float row (verified exact).
__device__ __forceinline__ float np_sumsq_512(const float* __restrict__ p) {
    float blk[4];
#pragma unroll
    for (int b = 0; b < 4; ++b) {
        const float* q = p + b * 128;
        float r[8];
#pragma unroll
        for (int j = 0; j < 8; ++j) r[j] = __fmul_rn(q[j], q[j]);
#pragma unroll
        for (int i = 1; i < 16; ++i)
#pragma unroll
            for (int j = 0; j < 8; ++j)
                r[j] = __fadd_rn(r[j], __fmul_rn(q[i * 8 + j], q[i * 8 + j]));
        blk[b] = __fadd_rn(__fadd_rn(__fadd_rn(r[0], r[1]), __fadd_rn(r[2], r[3])),
                           __fadd_rn(__fadd_rn(r[4], r[5]), __fadd_rn(r[6], r[7])));
    }
    return __fadd_rn(__fadd_rn(blk[0], blk[1]), __fadd_rn(blk[2], blk[3]));
}

// ---------------- kernel 1: row sums of squares ----------------
__global__ void k_rowsums(const float* __restrict__ zE, const float* __restrict__ cb,
                          float* __restrict__ sq, float* __restrict__ e2) {
    int row = blockIdx.x * 64 + threadIdx.x;
    if (row < ROWS) {
        sq[row] = np_sumsq_512(zE + (size_t)row * D);
    } else {
        e2[row - ROWS] = np_sumsq_512(cb + (size_t)(row - ROWS) * D);
    }
}

// A k-pair loader: 8 rows, wave-uniform address -> 8x s_load_dwordx2 (SGPRs)
__device__ __forceinline__ void loadA8(float2 (&a)[8], const float* __restrict__ zE,
                                       int rowTop, int kabs) {
#pragma unroll
    for (int i = 0; i < 8; ++i)
        a[i] = *(const float2*)(zE + (size_t)(rowTop + i) * D + kabs);
}

// ---------------- kernel 2: distance GEMM + fused partial argmin ----------------
// r10 structure + A moved from LDS to SGPRs (k-pair double-buffered s_load).
// Per wave-k LDS = 1 ds_read_b128 (B only) vs r10's 3 -> LDS pipe ~balanced
// with the 128 lane-FMA/cyc/CU compute rate. FMA = v_fmac v,s,v (1 SGPR legal).
// Grid XCD-swizzled as r10: XCD x serves code-split x&3 (cb slice L2-resident).
// Numerics per (row,code): m = fl(chain(k=0..383) + chain(k=384..511)),
// sequential ascending-k FMA; dist = fl(fl(s-2m)+e2). Bit-exact (rounds 4-10).
__global__ __launch_bounds__(256, 4)
void k_argmin(const float* __restrict__ zE, const float* __restrict__ cb,
              const float* __restrict__ sq, const float* __restrict__ e2,
              uint2* __restrict__ part) {
    __shared__ float Bs[BKK][BN];       // [k][code] 32 KiB (only LDS)

    const int p       = blockIdx.x;               // 0..4095
    const int x       = p & 7;                    // XCD
    const int s       = p >> 3;                   // 0..511
    const int cs      = x & 3;                    // code split, fixed per XCD
    const int rowBlk  = (x >> 2) * 512 + s;       // 0..1023
    const int rowBase = rowBlk * BM;
    const int tid     = threadIdx.x;
    const int lane    = tid & 63;
    const int lane4   = lane * 4;
    const int w8      = __builtin_amdgcn_readfirstlane((tid >> 6) * 8); // wave rows
    const int rowTop  = rowBase + w8;             // wave-uniform
    const int cg4     = (tid & 63) * 4;           // B-staging: 4 codes
    const int kq      = (tid >> 6) * 8;           // B-staging: 8 k's

    float srow[8];
#pragma unroll
    for (int i = 0; i < 8; ++i) srow[i] = sq[rowTop + i];

    float bvr[8];
    int   bir[8];
#pragma unroll
    for (int i = 0; i < 8; ++i) { bvr[i] = INFINITY; bir[i] = 0; }

    for (int ct = 0; ct < CODES_PER_SPLIT / BN; ++ct) {   // 8 code tiles
        const int codeBase = cs * CODES_PER_SPLIT + ct * BN;
        float acc[8][4], m1[8][4];
#pragma unroll
        for (int i = 0; i < 8; ++i)
#pragma unroll
            for (int j = 0; j < 4; ++j) { acc[i][j] = 0.0f; m1[i][j] = 0.0f; }

#pragma unroll 1
        for (int ks = 0; ks < D / BKK; ++ks) {            // 16 K stages, k ascending
            __syncthreads();
            {                                             // stage B (32 KiB), 4x4+4x4
                const float* g0 = cb + (size_t)(codeBase + cg4 + 0) * D + ks * BKK + kq;
                const float* g1 = cb + (size_t)(codeBase + cg4 + 1) * D + ks * BKK + kq;
                const float* g2 = cb + (size_t)(codeBase + cg4 + 2) * D + ks * BKK + kq;
                const float* g3 = cb + (size_t)(codeBase + cg4 + 3) * D + ks * BKK + kq;
                float4 u0 = *(const float4*)g0, v0 = *(const float4*)(g0 + 4);
                float4 u1 = *(const float4*)g1, v1 = *(const float4*)(g1 + 4);
                float4 u2 = *(const float4*)g2, v2 = *(const float4*)(g2 + 4);
                float4 u3 = *(const float4*)g3, v3 = *(const float4*)(g3 + 4);
#pragma unroll
                for (int j = 0; j < 4; ++j) {
                    float4 w;
                    w.x = f4c(u0, j); w.y = f4c(u1, j); w.z = f4c(u2, j); w.w = f4c(u3, j);
                    *(float4*)&Bs[kq + j][cg4] = w;
                }
#pragma unroll
                for (int j = 0; j < 4; ++j) {
                    float4 w;
                    w.x = f4c(v0, j); w.y = f4c(v1, j); w.z = f4c(v2, j); w.w = f4c(v3, j);
                    *(float4*)&Bs[kq + 4 + j][cg4] = w;
                }
            }
            __syncthreads();

            // compute: 16 k-pairs, A double-buffered in SGPRs (ascending k)
            float2 aA[8], aB[8];
            loadA8(aA, zE, rowTop, ks * BKK);
#pragma unroll 1
            for (int kp = 0; kp < 16; kp += 2) {
                loadA8(aB, zE, rowTop, ks * BKK + 2 * (kp + 1));
#pragma unroll
                for (int kk = 0; kk < 2; ++kk) {          // k = 2*kp + kk
                    float4 b = *(const float4*)&Bs[2 * kp + kk][lane4];
                    float bw[4] = {b.x, b.y, b.z, b.w};
#pragma unroll
                    for (int i = 0; i < 8; ++i) {
                        float a = kk ? aA[i].y : aA[i].x;
#pragma unroll
                        for (int j = 0; j < 4; ++j)
                            acc[i][j] = __builtin_fmaf(a, bw[j], acc[i][j]);
                    }
                }
                if (kp + 2 < 16)
                    loadA8(aA, zE, rowTop, ks * BKK + 2 * (kp + 2));
#pragma unroll
                for (int kk = 0; kk < 2; ++kk) {          // k = 2*(kp+1) + kk
                    float4 b = *(const float4*)&Bs[2 * (kp + 1) + kk][lane4];
                    float bw[4] = {b.x, b.y, b.z, b.w};
#pragma unroll
                    for (int i = 0; i < 8; ++i) {
                        float a = kk ? aB[i].y : aB[i].x;
#pragma unroll
                        for (int j = 0; j < 4; ++j)
                            acc[i][j] = __builtin_fmaf(a, bw[j], acc[i][j]);
                    }
                }
            }

            if (ks == KC / BKK - 1) {                     // close panel 1 (k=0..383)
#pragma unroll
                for (int i = 0; i < 8; ++i)
#pragma unroll
                    for (int j = 0; j < 4; ++j) { m1[i][j] = acc[i][j]; acc[i][j] = 0.0f; }
            }
        }

        // finalize: dist = fl(fl(s - 2*fl(S1+S2)) + e2); ascending code order
        float4 e4 = *(const float4*)(e2 + codeBase + lane4);
        float ec[4] = {e4.x, e4.y, e4.z, e4.w};
#pragma unroll
        for (int j = 0; j < 4; ++j) {
            int c = codeBase + lane4 + j;
#pragma unroll
            for (int i = 0; i < 8; ++i) {
                float m = __fadd_rn(m1[i][j], acc[i][j]);
                float d = __fadd_rn(__fsub_rn(srow[i], __fmul_rn(2.0f, m)), ec[j]);
                if (d < bvr[i]) { bvr[i] = d; bir[i] = c; }
            }
        }
    }

    // wave-level lexicographic (val, idx) argmin reduce; lanes hold disjoint codes
#pragma unroll
    for (int i = 0; i < 8; ++i) {
        float v = bvr[i];
        int   xx = bir[i];
#pragma unroll
        for (int off = 32; off; off >>= 1) {
            float v2 = __shfl_xor(v, off);
            int   x2 = __shfl_xor(xx, off);
            if (v2 < v || (v2 == v && x2 < xx)) { v = v2; xx = x2; }
        }
        if (lane == 0)
            part[(size_t)(rowTop + i) * NSPLIT + cs] =
                make_uint2(__float_as_uint(v), (unsigned)xx);
    }
}

// ---------------- kernel 3: reduce partials -> ids (f32 output) ----------------
__global__ void k_pick(const uint2* __restrict__ part, int* __restrict__ ids,
                       float* __restrict__ outIds) {
    int rr = blockIdx.x * blockDim.x + threadIdx.x;
    if (rr >= ROWS) return;
    float bvv = __uint_as_float(part[(size_t)rr * NSPLIT].x);
    int   bii = (int)part[(size_t)rr * NSPLIT].y;
    for (int cs2 = 1; cs2 < NSPLIT; ++cs2) {
        float v = __uint_as_float(part[(size_t)rr * NSPLIT + cs2].x);
        int   x = (int)part[(size_t)rr * NSPLIT + cs2].y;
        if (v < bvv || (v == bvv && x < bii)) { bvv = v; bii = x; }
    }
    bii = bii < 0 ? 0 : (bii > NCODES - 1 ? NCODES - 1 : bii);
    ids[rr] = bii;
    outIds[rr] = (float)bii;
}

// ---------------- kernel 4: gather z_q_st (f32) + loss partials ----------------
__global__ void k_gather(const float* __restrict__ zE, const float* __restrict__ cb,
                         const int* __restrict__ ids, float* __restrict__ outZ,
                         double* __restrict__ lossPart) {
    const int tid = threadIdx.x;
    double acc = 0.0;
#pragma unroll
    for (int it = 0; it < 4; ++it) {
        int chunk = blockIdx.x * 256 + tid + it * 1048576;   // float4 chunk id
        int row   = chunk >> 7;
        int koff  = (chunk & 127) << 2;
        int id    = ids[row];
        id = id < 0 ? 0 : (id > NCODES - 1 ? NCODES - 1 : id);
        float4 ze = *(const float4*)(zE + ((size_t)row << 9) + koff);
        float4 zq = *(const float4*)(cb + ((size_t)id << 9) + koff);
        float d0 = __fsub_rn(zq.x, ze.x);
        float d1 = __fsub_rn(zq.y, ze.y);
        float d2 = __fsub_rn(zq.z, ze.z);
        float d3 = __fsub_rn(zq.w, ze.w);
        float4 v;
        v.x = __fadd_rn(ze.x, d0);
        v.y = __fadd_rn(ze.y, d1);
        v.z = __fadd_rn(ze.z, d2);
        v.w = __fadd_rn(ze.w, d3);
        *reinterpret_cast<float4*>(outZ + ((size_t)chunk << 2)) = v;
        acc += (double)d0 * d0 + (double)d1 * d1 + (double)d2 * d2 + (double)d3 * d3;
    }
    for (int off = 32; off; off >>= 1) acc += __shfl_down(acc, off);
    __shared__ double sred[4];
    if ((tid & 63) == 0) sred[tid >> 6] = acc;
    __syncthreads();
    if (tid == 0) lossPart[blockIdx.x] = (sred[0] + sred[1]) + (sred[2] + sred[3]);
}

// ---------------- kernel 5: final loss (f32 output) ----------------
__global__ void k_loss(const double* __restrict__ lossPart, float* __restrict__ outLoss) {
    const int tid = threadIdx.x;
    double acc = 0.0;
    for (int i = tid; i < 4096; i += 256) acc += lossPart[i];
    for (int off = 32; off; off >>= 1) acc += __shfl_down(acc, off);
    __shared__ double sred[4];
    if ((tid & 63) == 0) sred[tid >> 6] = acc;
    __syncthreads();
    if (tid == 0) {
        double mean = ((sred[0] + sred[1]) + (sred[2] + sred[3])) / 16777216.0;
        float cl = (float)mean;
        *outLoss = __fadd_rn(cl, __fmul_rn(0.25f, cl));
    }
}

extern "C" void kernel_launch(void* const* d_in, const int* in_sizes, int n_in,
                              void* d_out, int out_size, void* d_ws, size_t ws_size,
                              hipStream_t stream) {
    (void)in_sizes; (void)n_in; (void)out_size; (void)ws_size;
    const float* zE = (const float*)d_in[0];
    const float* cb = (const float*)d_in[1];
    float* out = (float*)d_out;                    // f32 outputs, concatenated
    char* ws = (char*)d_ws;

    float*  sq       = (float*)(ws + 0);         // 32768 f32
    float*  e2       = (float*)(ws + 131072);    // 8192  f32
    int*    ids      = (int*)(ws + 163840);      // 32768 i32
    uint2*  part     = (uint2*)(ws + 294912);    // 32768*4 uint2 = 1 MiB
    double* lossPart = (double*)(ws + 1343488);  // 4096  f64

    k_rowsums<<<(ROWS + NCODES) / 64, 64, 0, stream>>>(zE, cb, sq, e2);
    k_argmin<<<NSPLIT * (ROWS / BM), 256, 0, stream>>>(zE, cb, sq, e2, part);
    k_pick<<<ROWS / 256, 256, 0, stream>>>(part, ids, out + 16777216);
    k_gather<<<4096, 256, 0, stream>>>(zE, cb, ids, out, lossPart);
    k_loss<<<1, 256, 0, stream>>>(lossPart, out + 16777216 + 32768);
}

// Round 12
// 1900.710 us; speedup vs baseline: 3.0859x; 2.0645x over previous
//
#include <hip/hip_runtime.h>

#define ROWS 32768      // B*T
#define D 512
#define NCODES 8192
#define KC 384          // OpenBLAS sgemm kc panel split (verified exact, rounds 4-11)
#define NSLOT 64

typedef _Float16 h8 __attribute__((ext_vector_type(8)));
typedef float f4v __attribute__((ext_vector_type(4)));

// numpy pairwise f32 sum of squares of a 512-float row (verified exact).
__device__ __forceinline__ float np_sumsq_512(const float* __restrict__ p) {
    float blk[4];
#pragma unroll
    for (int b = 0; b < 4; ++b) {
        const float* q = p + b * 128;
        float r[8];
#pragma unroll
        for (int j = 0; j < 8; ++j) r[j] = __fmul_rn(q[j], q[j]);
#pragma unroll
        for (int i = 1; i < 16; ++i)
#pragma unroll
            for (int j = 0; j < 8; ++j)
                r[j] = __fadd_rn(r[j], __fmul_rn(q[i * 8 + j], q[i * 8 + j]));
        blk[b] = __fadd_rn(__fadd_rn(__fadd_rn(r[0], r[1]), __fadd_rn(r[2], r[3])),
                           __fadd_rn(__fadd_rn(r[4], r[5]), __fadd_rn(r[6], r[7])));
    }
    return __fadd_rn(__fadd_rn(blk[0], blk[1]), __fadd_rn(blk[2], blk[3]));
}

// ---------------- kernel 1: row sums of squares + sum|x| ----------------
__global__ void k_rowsums(const float* __restrict__ zE, const float* __restrict__ cb,
                          float* __restrict__ sq, float* __restrict__ e2,
                          float* __restrict__ sabs) {
    int row = blockIdx.x * 64 + threadIdx.x;          // 640 x 64 = 40960
    if (row < ROWS) {
        const float* p = zE + (size_t)row * D;
        sq[row] = np_sumsq_512(p);
        float sa = 0.0f;
#pragma unroll 8
        for (int k = 0; k < D; ++k) sa += fabsf(p[k]);
        sabs[row] = sa;
    } else {
        e2[row - ROWS] = np_sumsq_512(cb + (size_t)(row - ROWS) * D);
    }
}

// ---------------- kernel 2: f32 -> f16 conversion (cb scaled by 2^12) ----------------
__global__ void k_half(const float* __restrict__ zE, const float* __restrict__ cb,
                       _Float16* __restrict__ zh, _Float16* __restrict__ ch) {
    int i = (blockIdx.x * 256 + threadIdx.x) * 8;     // 10240 blocks -> 20971520 floats
    if (i < ROWS * D) {
        float4 u = *(const float4*)(zE + i);
        float4 v = *(const float4*)(zE + i + 4);
        h8 o = {(_Float16)u.x, (_Float16)u.y, (_Float16)u.z, (_Float16)u.w,
                (_Float16)v.x, (_Float16)v.y, (_Float16)v.z, (_Float16)v.w};
        *(h8*)(zh + i) = o;
    } else {
        int j = i - ROWS * D;
        float4 u = *(const float4*)(cb + j);
        float4 v = *(const float4*)(cb + j + 4);
        h8 o = {(_Float16)(u.x * 4096.0f), (_Float16)(u.y * 4096.0f),
                (_Float16)(u.z * 4096.0f), (_Float16)(u.w * 4096.0f),
                (_Float16)(v.x * 4096.0f), (_Float16)(v.y * 4096.0f),
                (_Float16)(v.z * 4096.0f), (_Float16)(v.w * 4096.0f)};
        *(h8*)(ch + j) = o;
    }
}

// approx distance; IDENTICAL instruction sequence in both passes
__device__ __forceinline__ float dapprox(float s, float accv, float ecv) {
    float m = __fmul_rn(accv, 0.000244140625f);       // exact /4096
    return __fadd_rn(__fsub_rn(s, __fmul_rn(2.0f, m)), ecv);
}

// ---------------- kernels 3/4: fp16 MFMA distance passes ----------------
// block = 4 waves; wave tile 64 rows x 128 codes; mfma_f32_16x16x32_f16.
// A frag: lane holds zh[row0 + (lane&15)][k0 + (lane>>4)*8 + j]; B likewise from ch.
// D frag: col = lane&15, row = (lane>>4)*4 + j  (guide m89, verified).
// PASS 1: per-row min of d~ via shfl + global atomicMin (order-independent).
// PASS 2: collect codes with d~ <= min~ + WIN(row) into per-row slots.
template<int PASS>
__global__ __launch_bounds__(256, 2)
void k_mfma(const _Float16* __restrict__ zh, const _Float16* __restrict__ ch,
            const float* __restrict__ sq, const float* __restrict__ e2,
            const float* __restrict__ sabs, unsigned* __restrict__ minbits,
            int* __restrict__ cnt, int* __restrict__ cands) {
    const int p    = blockIdx.x;                      // 0..8191
    const int ct   = (p & 7) * 8 + ((p >> 3) & 7);    // code tile 0..63 (XCD-local cb slice)
    const int rt   = p >> 6;                          // row tile 0..127
    const int wave = threadIdx.x >> 6;
    const int lane = threadIdx.x & 63;
    const int l15  = lane & 15;
    const int lk   = lane >> 4;
    const int rw   = rt * 256 + wave * 64;            // wave's 64 rows
    const int cw   = ct * 128;                        // block's 128 codes

    f4v acc[4][8];
#pragma unroll
    for (int a = 0; a < 4; ++a)
#pragma unroll
        for (int b = 0; b < 8; ++b) acc[a][b] = (f4v){0.f, 0.f, 0.f, 0.f};

#pragma unroll 2
    for (int k0 = 0; k0 < D; k0 += 32) {
        h8 bf[8];
#pragma unroll
        for (int b = 0; b < 8; ++b)
            bf[b] = *(const h8*)(ch + (size_t)(cw + b * 16 + l15) * D + k0 + lk * 8);
#pragma unroll
        for (int a = 0; a < 4; ++a) {
            h8 af = *(const h8*)(zh + (size_t)(rw + a * 16 + l15) * D + k0 + lk * 8);
#pragma unroll
            for (int b = 0; b < 8; ++b)
                acc[a][b] = __builtin_amdgcn_mfma_f32_16x16x32_f16(af, bf[b], acc[a][b], 0, 0, 0);
        }
    }

#pragma unroll
    for (int a = 0; a < 4; ++a) {
        const int r0 = rw + a * 16 + lk * 4;
        float s0 = sq[r0 + 0], s1 = sq[r0 + 1], s2 = sq[r0 + 2], s3 = sq[r0 + 3];
        if (PASS == 1) {
            float rm0 = INFINITY, rm1 = INFINITY, rm2 = INFINITY, rm3 = INFINITY;
#pragma unroll
            for (int b = 0; b < 8; ++b) {
                float ecv = e2[cw + b * 16 + l15];
                rm0 = fminf(rm0, dapprox(s0, acc[a][b][0], ecv));
                rm1 = fminf(rm1, dapprox(s1, acc[a][b][1], ecv));
                rm2 = fminf(rm2, dapprox(s2, acc[a][b][2], ecv));
                rm3 = fminf(rm3, dapprox(s3, acc[a][b][3], ecv));
            }
            float rm[4] = {rm0, rm1, rm2, rm3};
#pragma unroll
            for (int jj = 0; jj < 4; ++jj) {
                float v = rm[jj];
                v = fminf(v, __shfl_xor(v, 1));
                v = fminf(v, __shfl_xor(v, 2));
                v = fminf(v, __shfl_xor(v, 4));
                v = fminf(v, __shfl_xor(v, 8));
                if (l15 == 0) atomicMin(&minbits[r0 + jj], __float_as_uint(v));
            }
        } else {
            float sv[4] = {s0, s1, s2, s3};
            float thr[4];
#pragma unroll
            for (int jj = 0; jj < 4; ++jj)
                thr[jj] = __uint_as_float(minbits[r0 + jj])
                        + (sabs[r0 + jj] * 8e-7f + 6e-4f);
#pragma unroll
            for (int b = 0; b < 8; ++b) {
                int   code = cw + b * 16 + l15;
                float ecv  = e2[code];
#pragma unroll
                for (int jj = 0; jj < 4; ++jj) {
                    float d = dapprox(sv[jj], acc[a][b][jj], ecv);
                    if (d <= thr[jj]) {
                        int sl = atomicAdd(&cnt[r0 + jj], 1);
                        if (sl < NSLOT) cands[(size_t)(r0 + jj) * NSLOT + sl] = code;
                    }
                }
            }
        }
    }
}

// exact distance: verified dual-chain (rounds 4-11), sequential ascending-k FMA
__device__ __forceinline__ float exact_d(const float* __restrict__ xr,
                                         const float* __restrict__ er,
                                         float s, float ev) {
    float m1 = 0.0f, m2 = 0.0f;
#pragma unroll 8
    for (int k = 0; k < KC; ++k) m1 = __builtin_fmaf(xr[k], er[k], m1);
#pragma unroll 8
    for (int k = KC; k < D; ++k) m2 = __builtin_fmaf(xr[k], er[k], m2);
    float m = __fadd_rn(m1, m2);
    return __fadd_rn(__fsub_rn(s, __fmul_rn(2.0f, m)), ev);
}

// ---------------- kernel 5: exact rescore of candidates -> ids ----------------
__global__ void k_rescore(const float* __restrict__ zE, const float* __restrict__ cb,
                          const float* __restrict__ sq, const float* __restrict__ e2,
                          const int* __restrict__ cnt, const int* __restrict__ cands,
                          int* __restrict__ ids, float* __restrict__ outIds) {
    int row = blockIdx.x * 256 + threadIdx.x;         // 128 blocks
    if (row >= ROWS) return;
    const float* xr = zE + (size_t)row * D;
    float s = sq[row];
    int   n = cnt[row];
    float bd = INFINITY;
    int   bi = NCODES - 1;
    if (n <= NSLOT) {
        for (int t = 0; t < n; ++t) {
            int c = cands[(size_t)row * NSLOT + t];
            float d = exact_d(xr, cb + (size_t)c * D, s, e2[c]);
            if (d < bd || (d == bd && c < bi)) { bd = d; bi = c; }
        }
    } else {                                          // sound fallback (never triggers)
        for (int c = 0; c < NCODES; ++c) {
            float d = exact_d(xr, cb + (size_t)c * D, s, e2[c]);
            if (d < bd) { bd = d; bi = c; }
        }
    }
    bi = bi < 0 ? 0 : (bi > NCODES - 1 ? NCODES - 1 : bi);
    ids[row] = bi;
    outIds[row] = (float)bi;
}

// ---------------- kernel 6: gather z_q_st (f32) + loss partials (verified) ----------------
__global__ void k_gather(const float* __restrict__ zE, const float* __restrict__ cb,
                         const int* __restrict__ ids, float* __restrict__ outZ,
                         double* __restrict__ lossPart) {
    const int tid = threadIdx.x;
    double acc = 0.0;
#pragma unroll
    for (int it = 0; it < 4; ++it) {
        int chunk = blockIdx.x * 256 + tid + it * 1048576;
        int row   = chunk >> 7;
        int koff  = (chunk & 127) << 2;
        int id    = ids[row];
        id = id < 0 ? 0 : (id > NCODES - 1 ? NCODES - 1 : id);
        float4 ze = *(const float4*)(zE + ((size_t)row << 9) + koff);
        float4 zq = *(const float4*)(cb + ((size_t)id << 9) + koff);
        float d0 = __fsub_rn(zq.x, ze.x);
        float d1 = __fsub_rn(zq.y, ze.y);
        float d2 = __fsub_rn(zq.z, ze.z);
        float d3 = __fsub_rn(zq.w, ze.w);
        float4 v;
        v.x = __fadd_rn(ze.x, d0);
        v.y = __fadd_rn(ze.y, d1);
        v.z = __fadd_rn(ze.z, d2);
        v.w = __fadd_rn(ze.w, d3);
        *reinterpret_cast<float4*>(outZ + ((size_t)chunk << 2)) = v;
        acc += (double)d0 * d0 + (double)d1 * d1 + (double)d2 * d2 + (double)d3 * d3;
    }
    for (int off = 32; off; off >>= 1) acc += __shfl_down(acc, off);
    __shared__ double sred[4];
    if ((tid & 63) == 0) sred[tid >> 6] = acc;
    __syncthreads();
    if (tid == 0) lossPart[blockIdx.x] = (sred[0] + sred[1]) + (sred[2] + sred[3]);
}

// ---------------- kernel 7: final loss (verified) ----------------
__global__ void k_loss(const double* __restrict__ lossPart, float* __restrict__ outLoss) {
    const int tid = threadIdx.x;
    double acc = 0.0;
    for (int i = tid; i < 4096; i += 256) acc += lossPart[i];
    for (int off = 32; off; off >>= 1) acc += __shfl_down(acc, off);
    __shared__ double sred[4];
    if ((tid & 63) == 0) sred[tid >> 6] = acc;
    __syncthreads();
    if (tid == 0) {
        double mean = ((sred[0] + sred[1]) + (sred[2] + sred[3])) / 16777216.0;
        float cl = (float)mean;
        *outLoss = __fadd_rn(cl, __fmul_rn(0.25f, cl));
    }
}

extern "C" void kernel_launch(void* const* d_in, const int* in_sizes, int n_in,
                              void* d_out, int out_size, void* d_ws, size_t ws_size,
                              hipStream_t stream) {
    (void)in_sizes; (void)n_in; (void)out_size; (void)ws_size;
    const float* zE = (const float*)d_in[0];
    const float* cb = (const float*)d_in[1];
    float* out = (float*)d_out;
    char*  ws  = (char*)d_ws;
    char*  ob  = (char*)d_out;

    // ws scratch (small)
    float*    sq       = (float*)(ws + 0);            // 128 KiB
    float*    e2       = (float*)(ws + 131072);       // 32 KiB
    int*      ids      = (int*)(ws + 163840);         // 128 KiB
    float*    sabs     = (float*)(ws + 294912);       // 128 KiB
    unsigned* minbits  = (unsigned*)(ws + 425984);    // 128 KiB
    int*      cnt      = (int*)(ws + 557056);         // 128 KiB
    double*   lossPart = (double*)(ws + 1343488);     // 32 KiB

    // big scratch inside d_out region 0 (overwritten by k_gather afterwards)
    _Float16* zh    = (_Float16*)(ob + 0);            // 32 MiB
    _Float16* ch    = (_Float16*)(ob + 33554432);     // 8 MiB
    int*      cands = (int*)(ob + 41943040);          // 8 MiB

    k_rowsums<<<(ROWS + NCODES) / 64, 64, 0, stream>>>(zE, cb, sq, e2, sabs);
    k_half<<<(ROWS + NCODES) * (D / 8) / 256, 256, 0, stream>>>(zE, cb, zh, ch);
    hipMemsetAsync(minbits, 0x7F, 131072, stream);    // 3.39e38 > any d~
    hipMemsetAsync(cnt, 0, 131072, stream);
    k_mfma<1><<<8192, 256, 0, stream>>>(zh, ch, sq, e2, sabs, minbits, cnt, cands);
    k_mfma<2><<<8192, 256, 0, stream>>>(zh, ch, sq, e2, sabs, minbits, cnt, cands);
    k_rescore<<<ROWS / 256, 256, 0, stream>>>(zE, cb, sq, e2, cnt, cands,
                                              ids, out + 16777216);
    k_gather<<<4096, 256, 0, stream>>>(zE, cb, ids, out, lossPart);
    k_loss<<<1, 256, 0, stream>>>(lossPart, out + 16777216 + 32768);
}